// Round 9
// baseline (40.932 us; speedup 1.0000x reference)
//
#include <hip/hip_runtime.h>
#include <math.h>

#define NQ   4
#define DIM  16
#define NL   6
#define TPB  256

#define INV2PI 0.15915494309189535f

// Hardware trig: v_sin_f32 / v_cos_f32 take input in revolutions.
__device__ inline float hsin(float rad) { return __builtin_amdgcn_sinf(rad * INV2PI); }
__device__ inline float hcos(float rad) { return __builtin_amdgcn_cosf(rad * INV2PI); }

struct Perm { int p[DIM]; };

__host__ __device__ constexpr int cnotp(int c, int t, int idx) {
    return ((idx >> (3 - c)) & 1) ? (idx ^ (1 << (3 - t))) : idx;
}

__host__ __device__ constexpr Perm ring_perm(int r) {
    Perm P{};
    for (int j = 0; j < DIM; ++j) P.p[j] = j;
    for (int i = 0; i < NQ; ++i) {
        Perm Q{};
        for (int j = 0; j < DIM; ++j) Q.p[j] = P.p[cnotp(i, (i + r) % NQ, j)];
        P = Q;
    }
    return P;
}

__device__ inline float4 f4fma(float4 a, float s, float4 c) {
    return make_float4(fmaf(a.x, s, c.x), fmaf(a.y, s, c.y),
                       fmaf(a.z, s, c.z), fmaf(a.w, s, c.w));
}

// ---------------------------------------------------------------------------
// Setup (one block): build U in LDS, then ReM_q = Re(U^dag D_q U), then the
// 81x4 contraction tensor C to global ws:
//   out_q = sum_{a,b,c,d in 0..2} C[a,b,c,d][q] * u0_a u1_b u2_c u3_d,
//   u_i = (1, cos x_i, sin x_i).   (validated rounds 2-8)
// ---------------------------------------------------------------------------
__global__ __launch_bounds__(384) void build_all(const float* __restrict__ w,
                                                 float* __restrict__ Cg) {
    __shared__ float Ulds[DIM * DIM * 2];   // [(row*16+col)*2 + {re,im}]
    __shared__ float ReMs[DIM * DIM * 4];   // [(k*16+j)*4 + q]
    const int t = threadIdx.x;

    if (t < DIM) {
        float cr[DIM], ci[DIM];
        #pragma unroll
        for (int j = 0; j < DIM; ++j) { cr[j] = (j == t) ? 1.0f : 0.0f; ci[j] = 0.0f; }

        #pragma unroll
        for (int l = 0; l < NL; ++l) {
            #pragma unroll
            for (int i = 0; i < NQ; ++i) {
                const float phi = w[(l * NQ + i) * 3 + 0];
                const float th  = w[(l * NQ + i) * 3 + 1];
                const float om  = w[(l * NQ + i) * 3 + 2];
                const float ct = hcos(0.5f * th),          st = hsin(0.5f * th);
                const float cp = hcos(0.5f * (phi + om)),  sp = hsin(0.5f * (phi + om));
                const float cm = hcos(0.5f * (phi - om)),  sm = hsin(0.5f * (phi - om));
                const float g00r =  cp * ct, g00i = -sp * ct;
                const float g01r = -cm * st, g01i = -sm * st;
                const float g10r =  cm * st, g10i = -sm * st;
                const float g11r =  cp * ct, g11i =  sp * ct;

                const int stride = 1 << (3 - i);
                #pragma unroll
                for (int j = 0; j < DIM; ++j) {
                    if (j & stride) continue;
                    const int j1 = j | stride;
                    const float a0r = cr[j],  a0i = ci[j];
                    const float a1r = cr[j1], a1i = ci[j1];
                    cr[j]  = g00r * a0r - g00i * a0i + g01r * a1r - g01i * a1i;
                    ci[j]  = g00r * a0i + g00i * a0r + g01r * a1i + g01i * a1r;
                    cr[j1] = g10r * a0r - g10i * a0i + g11r * a1r - g11i * a1i;
                    ci[j1] = g10r * a0i + g10i * a0r + g11r * a1i + g11i * a1r;
                }
            }
            constexpr Perm RP[3] = { ring_perm(1), ring_perm(2), ring_perm(3) };
            const Perm& P = RP[l % 3];
            float nr[DIM], ni[DIM];
            #pragma unroll
            for (int j = 0; j < DIM; ++j) { nr[j] = cr[P.p[j]]; ni[j] = ci[P.p[j]]; }
            #pragma unroll
            for (int j = 0; j < DIM; ++j) { cr[j] = nr[j]; ci[j] = ni[j]; }
        }
        #pragma unroll
        for (int j = 0; j < DIM; ++j) {
            Ulds[(j * DIM + t) * 2 + 0] = cr[j];
            Ulds[(j * DIM + t) * 2 + 1] = ci[j];
        }
    }
    __syncthreads();

    if (t < 256) {
        const int j = t & 15, k = t >> 4;
        float s[4] = {0.f, 0.f, 0.f, 0.f};
        #pragma unroll
        for (int m = 0; m < DIM; ++m) {
            const float rr = Ulds[(m * DIM + j) * 2 + 0] * Ulds[(m * DIM + k) * 2 + 0]
                           + Ulds[(m * DIM + j) * 2 + 1] * Ulds[(m * DIM + k) * 2 + 1];
            #pragma unroll
            for (int q = 0; q < 4; ++q)
                s[q] += ((m >> (3 - q)) & 1) ? -rr : rr;
        }
        #pragma unroll
        for (int q = 0; q < 4; ++q) ReMs[(k * DIM + j) * 4 + q] = s[q];
    }
    __syncthreads();

    if (t < 324) {
        const int q = t & 3;
        const int r = t >> 2;                 // 0..80
        int e[4];
        e[3] = r % 3; e[2] = (r / 3) % 3; e[1] = (r / 9) % 3; e[0] = r / 27;
        float sum = 0.f;
        #pragma unroll
        for (int o = 0; o < 16; ++o) {
            int j = 0, k = 0; float wgt = 1.f;
            #pragma unroll
            for (int i = 0; i < 4; ++i) {
                const int oi = (o >> i) & 1;
                int bj, bk; float wi;
                if (e[i] == 0)      { bj = oi; bk = oi;     wi = 0.5f; }
                else if (e[i] == 1) { bj = oi; bk = oi;     wi = oi ? -0.5f : 0.5f; }
                else                { bj = oi; bk = oi ^ 1; wi = 0.5f; }
                j |= bj << (3 - i); k |= bk << (3 - i); wgt *= wi;
            }
            sum += wgt * ReMs[(k * DIM + j) * 4 + q];
        }
        Cg[r * 4 + q] = sum;
    }
}

// ---------------------------------------------------------------------------
// Main kernel, round 9. Two remaining theories for the ~24 us qsim plateau:
//  T1 latency chains (9 loads -> waitcnt -> FMA per unroll-1 iter, unhidden)
//  T2 VMEM-issue cost of 81 broadcast loads/element (~11 cyc/load implied)
// This version attacks both: ELEM=2 halves loads/element (T2), b-level fully
// unrolled gives 27-load bursts with deep ILP and only 3 stall points (T1).
// a-level stays unroll-1 (round-4: full unroll -> 256 VGPR spill). All L
// indices are compile-time constants (no address-taken locals, rule 20).
// ---------------------------------------------------------------------------
__global__ __launch_bounds__(TPB) void qsim(const float4* __restrict__ x,
                                            const float4* __restrict__ Cg,
                                            float4* __restrict__ out, int T) {
    const int tid = blockIdx.x * TPB + threadIdx.x;
    if (tid >= T) return;

    const float4 xa = x[tid];
    const float4 xb = x[tid + T];
    const float ca0 = hcos(xa.x), sa0 = hsin(xa.x);
    const float ca1 = hcos(xa.y), sa1 = hsin(xa.y);
    const float ca2 = hcos(xa.z), sa2 = hsin(xa.z);
    const float ca3 = hcos(xa.w), sa3 = hsin(xa.w);
    const float cb0 = hcos(xb.x), sb0 = hsin(xb.x);
    const float cb1 = hcos(xb.y), sb1 = hsin(xb.y);
    const float cb2 = hcos(xb.z), sb2 = hsin(xb.z);
    const float cb3 = hcos(xb.w), sb3 = hsin(xb.w);

    float4 accA = make_float4(0.f, 0.f, 0.f, 0.f);
    float4 accB = make_float4(0.f, 0.f, 0.f, 0.f);

    #pragma unroll 1
    for (int a = 0; a < 3; ++a) {
        float4 L[27];
        #pragma unroll
        for (int m = 0; m < 27; ++m) L[m] = Cg[a * 27 + m];

        const float waA = (a == 0) ? 1.f : ((a == 1) ? ca0 : sa0);
        const float waB = (a == 0) ? 1.f : ((a == 1) ? cb0 : sb0);

        #pragma unroll
        for (int b = 0; b < 3; ++b) {
            const float wA = waA * ((b == 0) ? 1.f : ((b == 1) ? ca1 : sa1));
            const float wB = waB * ((b == 0) ? 1.f : ((b == 1) ? cb1 : sb1));

            {   // element A: contract qubit3 (d), qubit2 (c), fold (a,b)
                float4 F  = f4fma(L[b*9+2], sa3, f4fma(L[b*9+1], ca3, L[b*9+0]));
                float4 E1 = f4fma(L[b*9+5], sa3, f4fma(L[b*9+4], ca3, L[b*9+3]));
                F = f4fma(E1, ca2, F);
                float4 E2 = f4fma(L[b*9+8], sa3, f4fma(L[b*9+7], ca3, L[b*9+6]));
                F = f4fma(E2, sa2, F);
                accA = f4fma(F, wA, accA);
            }
            {   // element B
                float4 F  = f4fma(L[b*9+2], sb3, f4fma(L[b*9+1], cb3, L[b*9+0]));
                float4 E1 = f4fma(L[b*9+5], sb3, f4fma(L[b*9+4], cb3, L[b*9+3]));
                F = f4fma(E1, cb2, F);
                float4 E2 = f4fma(L[b*9+8], sb3, f4fma(L[b*9+7], cb3, L[b*9+6]));
                F = f4fma(E2, sb2, F);
                accB = f4fma(F, wB, accB);
            }
        }
    }

    out[tid] = accA;
    out[tid + T] = accB;
}

extern "C" void kernel_launch(void* const* d_in, const int* in_sizes, int n_in,
                              void* d_out, int out_size, void* d_ws, size_t ws_size,
                              hipStream_t stream) {
    const float* x = (const float*)d_in[0];   // (B, 4) f32
    const float* w = (const float*)d_in[1];   // (6, 4, 3) f32
    float* Cg = (float*)d_ws;                 // 81 * float4 = 1296 B
    const int B = in_sizes[0] / NQ;           // 1048576
    const int T = B / 2;                      // ELEM=2

    build_all<<<1, 384, 0, stream>>>(w, Cg);
    // DIAGNOSTIC double-launch (deterministic: qsim is idempotent).
    // total = OH + build + 2*q  ->  q = (total - 8.5us)/2, readable from the
    // bench number even while qsim stays below the rocprof top-5 cutoff.
    qsim<<<(T + TPB - 1) / TPB, TPB, 0, stream>>>((const float4*)x, (const float4*)Cg,
                                                  (float4*)d_out, T);
    qsim<<<(T + TPB - 1) / TPB, TPB, 0, stream>>>((const float4*)x, (const float4*)Cg,
                                                  (float4*)d_out, T);
}

// Round 10
// 23.378 us; speedup vs baseline: 1.7509x; 1.7509x over previous
//
#include <hip/hip_runtime.h>
#include <math.h>

#define NQ   4
#define DIM  16
#define NL   6
#define TPB  256

#define INV2PI 0.15915494309189535f

// Hardware trig: v_sin_f32 / v_cos_f32 take input in revolutions.
__device__ inline float hsin(float rad) { return __builtin_amdgcn_sinf(rad * INV2PI); }
__device__ inline float hcos(float rad) { return __builtin_amdgcn_cosf(rad * INV2PI); }

__host__ __device__ constexpr int cnotp(int c, int t, int idx) {
    return ((idx >> (3 - c)) & 1) ? (idx ^ (1 << (3 - t))) : idx;
}

__device__ inline float4 f4fma(float4 a, float s, float4 c) {
    return make_float4(fmaf(a.x, s, c.x), fmaf(a.y, s, c.y),
                       fmaf(a.z, s, c.z), fmaf(a.w, s, c.w));
}

// ---------------------------------------------------------------------------
// Setup (one block, 384 threads). Round-10 change: phase 0 is now PARALLEL —
// 256 threads hold one complex amplitude each (thread = col*16+row, one
// column of U per 16-lane group). Gate pairs (row, row^stride) exchange via
// in-wave __shfl_xor; ring perms via __shfl with a bit-ops source lane.
// Was: 16 lanes of one wave doing a serial 24x128-FMA chain (~4-5 us).
// Phases 1-2 (ReM, C-tensor) unchanged (validated rounds 2-9).
// ---------------------------------------------------------------------------
__global__ __launch_bounds__(384) void build_all(const float* __restrict__ w,
                                                 float* __restrict__ Cg) {
    __shared__ float Ulds[DIM * DIM * 2];   // [(row*16+col)*2 + {re,im}]
    __shared__ float ReMs[DIM * DIM * 4];   // [(k*16+j)*4 + q]
    const int t = threadIdx.x;

    if (t < 256) {                           // waves 0-3: t<256 is wave-uniform
        const int lane = t & 63;
        const int row  = lane & 15;          // amplitude index within column
        const int col  = t >> 4;             // which column of U
        float cr = (row == col) ? 1.0f : 0.0f;
        float ci = 0.0f;

        #pragma unroll
        for (int l = 0; l < NL; ++l) {
            #pragma unroll
            for (int i = 0; i < NQ; ++i) {
                const float phi = w[(l * NQ + i) * 3 + 0];
                const float th  = w[(l * NQ + i) * 3 + 1];
                const float om  = w[(l * NQ + i) * 3 + 2];
                const float ct = hcos(0.5f * th),         st = hsin(0.5f * th);
                const float cp = hcos(0.5f * (phi + om)), sp = hsin(0.5f * (phi + om));
                const float cm = hcos(0.5f * (phi - om)), sm = hsin(0.5f * (phi - om));
                const float g00r =  cp * ct, g00i = -sp * ct;
                const float g01r = -cm * st, g01i = -sm * st;
                const float g10r =  cm * st, g10i = -sm * st;
                const float g11r =  cp * ct, g11i =  sp * ct;

                const int stride = 1 << (3 - i);
                const float pcr = __shfl_xor(cr, stride);
                const float pci = __shfl_xor(ci, stride);
                const bool hi = (row & stride) != 0;
                // a = amplitude in the 0-slot of the pair, b = 1-slot
                const float a_r = hi ? pcr : cr,  a_i = hi ? pci : ci;
                const float b_r = hi ? cr  : pcr, b_i = hi ? ci  : pci;
                const float G0r = hi ? g10r : g00r, G0i = hi ? g10i : g00i;
                const float G1r = hi ? g11r : g01r, G1i = hi ? g11i : g01i;
                cr = G0r * a_r - G0i * a_i + G1r * b_r - G1i * b_i;
                ci = G0r * a_i + G0i * a_r + G1r * b_i + G1i * b_r;
            }
            // ring permutation: new[row] = old[P(row)],
            // P = cnot0 . cnot1 . cnot2 . cnot3 (apply cnot3 innermost)
            const int r = l % 3 + 1;
            int src = row;
            src = cnotp(3, (3 + r) & 3, src);
            src = cnotp(2, (2 + r) & 3, src);
            src = cnotp(1, (1 + r) & 3, src);
            src = cnotp(0, (0 + r) & 3, src);
            const int srcLane = (lane & ~15) | src;
            cr = __shfl(cr, srcLane);
            ci = __shfl(ci, srcLane);
        }
        Ulds[(row * DIM + col) * 2 + 0] = cr;
        Ulds[(row * DIM + col) * 2 + 1] = ci;
    }
    __syncthreads();

    // Phase 1: ReM_q[j,k] = sum_m sgn_q(m) * (Ur[m,j]Ur[m,k] + Ui[m,j]Ui[m,k])
    if (t < 256) {
        const int j = t & 15, k = t >> 4;
        float s[4] = {0.f, 0.f, 0.f, 0.f};
        #pragma unroll
        for (int m = 0; m < DIM; ++m) {
            const float rr = Ulds[(m * DIM + j) * 2 + 0] * Ulds[(m * DIM + k) * 2 + 0]
                           + Ulds[(m * DIM + j) * 2 + 1] * Ulds[(m * DIM + k) * 2 + 1];
            #pragma unroll
            for (int q = 0; q < 4; ++q)
                s[q] += ((m >> (3 - q)) & 1) ? -rr : rr;
        }
        #pragma unroll
        for (int q = 0; q < 4; ++q) ReMs[(k * DIM + j) * 4 + q] = s[q];
    }
    __syncthreads();

    // Phase 2: C[r][q], r = a*27+b*9+c*3+d (coeff basis per qubit: 1,cos,sin)
    if (t < 324) {
        const int q = t & 3;
        const int r = t >> 2;                 // 0..80
        int e[4];
        e[3] = r % 3; e[2] = (r / 3) % 3; e[1] = (r / 9) % 3; e[0] = r / 27;
        float sum = 0.f;
        #pragma unroll
        for (int o = 0; o < 16; ++o) {
            int j = 0, k = 0; float wgt = 1.f;
            #pragma unroll
            for (int i = 0; i < 4; ++i) {
                const int oi = (o >> i) & 1;
                int bj, bk; float wi;
                if (e[i] == 0)      { bj = oi; bk = oi;     wi = 0.5f; }
                else if (e[i] == 1) { bj = oi; bk = oi;     wi = oi ? -0.5f : 0.5f; }
                else                { bj = oi; bk = oi ^ 1; wi = 0.5f; }
                j |= bj << (3 - i); k |= bk << (3 - i); wgt *= wi;
            }
            sum += wgt * ReMs[(k * DIM + j) * 4 + q];
        }
        Cg[r * 4 + q] = sum;
    }
}

// ---------------------------------------------------------------------------
// Main kernel: r9 structure verbatim (validated: q ~15-16 us via the
// double-launch algebra, 1.6x better than ELEM=1/ELEM=4 variants).
// ELEM=2, b-level fully unrolled (27-load bursts, 3 stall points), a-level
// unroll-1 (round-4: full unroll -> 256 VGPR spill).
// ---------------------------------------------------------------------------
__global__ __launch_bounds__(TPB) void qsim(const float4* __restrict__ x,
                                            const float4* __restrict__ Cg,
                                            float4* __restrict__ out, int T) {
    const int tid = blockIdx.x * TPB + threadIdx.x;
    if (tid >= T) return;

    const float4 xa = x[tid];
    const float4 xb = x[tid + T];
    const float ca0 = hcos(xa.x), sa0 = hsin(xa.x);
    const float ca1 = hcos(xa.y), sa1 = hsin(xa.y);
    const float ca2 = hcos(xa.z), sa2 = hsin(xa.z);
    const float ca3 = hcos(xa.w), sa3 = hsin(xa.w);
    const float cb0 = hcos(xb.x), sb0 = hsin(xb.x);
    const float cb1 = hcos(xb.y), sb1 = hsin(xb.y);
    const float cb2 = hcos(xb.z), sb2 = hsin(xb.z);
    const float cb3 = hcos(xb.w), sb3 = hsin(xb.w);

    float4 accA = make_float4(0.f, 0.f, 0.f, 0.f);
    float4 accB = make_float4(0.f, 0.f, 0.f, 0.f);

    #pragma unroll 1
    for (int a = 0; a < 3; ++a) {
        float4 L[27];
        #pragma unroll
        for (int m = 0; m < 27; ++m) L[m] = Cg[a * 27 + m];

        const float waA = (a == 0) ? 1.f : ((a == 1) ? ca0 : sa0);
        const float waB = (a == 0) ? 1.f : ((a == 1) ? cb0 : sb0);

        #pragma unroll
        for (int b = 0; b < 3; ++b) {
            const float wA = waA * ((b == 0) ? 1.f : ((b == 1) ? ca1 : sa1));
            const float wB = waB * ((b == 0) ? 1.f : ((b == 1) ? cb1 : sb1));

            {   // element A: contract qubit3 (d), qubit2 (c), fold (a,b)
                float4 F  = f4fma(L[b*9+2], sa3, f4fma(L[b*9+1], ca3, L[b*9+0]));
                float4 E1 = f4fma(L[b*9+5], sa3, f4fma(L[b*9+4], ca3, L[b*9+3]));
                F = f4fma(E1, ca2, F);
                float4 E2 = f4fma(L[b*9+8], sa3, f4fma(L[b*9+7], ca3, L[b*9+6]));
                F = f4fma(E2, sa2, F);
                accA = f4fma(F, wA, accA);
            }
            {   // element B
                float4 F  = f4fma(L[b*9+2], sb3, f4fma(L[b*9+1], cb3, L[b*9+0]));
                float4 E1 = f4fma(L[b*9+5], sb3, f4fma(L[b*9+4], cb3, L[b*9+3]));
                F = f4fma(E1, cb2, F);
                float4 E2 = f4fma(L[b*9+8], sb3, f4fma(L[b*9+7], cb3, L[b*9+6]));
                F = f4fma(E2, sb2, F);
                accB = f4fma(F, wB, accB);
            }
        }
    }

    out[tid] = accA;
    out[tid + T] = accB;
}

extern "C" void kernel_launch(void* const* d_in, const int* in_sizes, int n_in,
                              void* d_out, int out_size, void* d_ws, size_t ws_size,
                              hipStream_t stream) {
    const float* x = (const float*)d_in[0];   // (B, 4) f32
    const float* w = (const float*)d_in[1];   // (6, 4, 3) f32
    float* Cg = (float*)d_ws;                 // 81 * float4 = 1296 B
    const int B = in_sizes[0] / NQ;           // 1048576
    const int T = B / 2;                      // ELEM=2

    build_all<<<1, 384, 0, stream>>>(w, Cg);
    qsim<<<(T + TPB - 1) / TPB, TPB, 0, stream>>>((const float4*)x, (const float4*)Cg,
                                                  (float4*)d_out, T);
}

// Round 12
// 23.373 us; speedup vs baseline: 1.7513x; 1.0002x over previous
//
#include <hip/hip_runtime.h>
#include <math.h>

#define NQ   4
#define DIM  16
#define NL   6
#define TPB  256

#define INV2PI 0.15915494309189535f

typedef float f4v __attribute__((ext_vector_type(4)));

// Hardware trig: v_sin_f32 / v_cos_f32 take input in revolutions.
__device__ inline float hsin(float rad) { return __builtin_amdgcn_sinf(rad * INV2PI); }
__device__ inline float hcos(float rad) { return __builtin_amdgcn_cosf(rad * INV2PI); }

__host__ __device__ constexpr int cnotp(int c, int t, int idx) {
    return ((idx >> (3 - c)) & 1) ? (idx ^ (1 << (3 - t))) : idx;
}

__device__ inline f4v vfma(f4v a, float s, f4v c) {
    f4v r;
    r.x = fmaf(a.x, s, c.x);
    r.y = fmaf(a.y, s, c.y);
    r.z = fmaf(a.z, s, c.z);
    r.w = fmaf(a.w, s, c.w);
    return r;
}

// ---------------------------------------------------------------------------
// Setup (one block, 384 threads): parallel U build via __shfl_xor (r10,
// validated), then ReM_q = Re(U^dag D_q U), then the 81x4 tensor C to ws:
//   out_q = sum_{a,b,c,d} C[a,b,c,d][q] * u0_a u1_b u2_c u3_d,
//   u_i = (1, cos x_i, sin x_i).
// ---------------------------------------------------------------------------
__global__ __launch_bounds__(384) void build_all(const float* __restrict__ w,
                                                 float* __restrict__ Cg) {
    __shared__ float Ulds[DIM * DIM * 2];   // [(row*16+col)*2 + {re,im}]
    __shared__ float ReMs[DIM * DIM * 4];   // [(k*16+j)*4 + q]
    const int t = threadIdx.x;

    if (t < 256) {
        const int lane = t & 63;
        const int row  = lane & 15;
        const int col  = t >> 4;
        float cr = (row == col) ? 1.0f : 0.0f;
        float ci = 0.0f;

        #pragma unroll
        for (int l = 0; l < NL; ++l) {
            #pragma unroll
            for (int i = 0; i < NQ; ++i) {
                const float phi = w[(l * NQ + i) * 3 + 0];
                const float th  = w[(l * NQ + i) * 3 + 1];
                const float om  = w[(l * NQ + i) * 3 + 2];
                const float ct = hcos(0.5f * th),         st = hsin(0.5f * th);
                const float cp = hcos(0.5f * (phi + om)), sp = hsin(0.5f * (phi + om));
                const float cm = hcos(0.5f * (phi - om)), sm = hsin(0.5f * (phi - om));
                const float g00r =  cp * ct, g00i = -sp * ct;
                const float g01r = -cm * st, g01i = -sm * st;
                const float g10r =  cm * st, g10i = -sm * st;
                const float g11r =  cp * ct, g11i =  sp * ct;

                const int stride = 1 << (3 - i);
                const float pcr = __shfl_xor(cr, stride);
                const float pci = __shfl_xor(ci, stride);
                const bool hi = (row & stride) != 0;
                const float a_r = hi ? pcr : cr,  a_i = hi ? pci : ci;
                const float b_r = hi ? cr  : pcr, b_i = hi ? ci  : pci;
                const float G0r = hi ? g10r : g00r, G0i = hi ? g10i : g00i;
                const float G1r = hi ? g11r : g01r, G1i = hi ? g11i : g01i;
                cr = G0r * a_r - G0i * a_i + G1r * b_r - G1i * b_i;
                ci = G0r * a_i + G0i * a_r + G1r * b_i + G1i * b_r;
            }
            const int r = l % 3 + 1;
            int src = row;
            src = cnotp(3, (3 + r) & 3, src);
            src = cnotp(2, (2 + r) & 3, src);
            src = cnotp(1, (1 + r) & 3, src);
            src = cnotp(0, (0 + r) & 3, src);
            const int srcLane = (lane & ~15) | src;
            cr = __shfl(cr, srcLane);
            ci = __shfl(ci, srcLane);
        }
        Ulds[(row * DIM + col) * 2 + 0] = cr;
        Ulds[(row * DIM + col) * 2 + 1] = ci;
    }
    __syncthreads();

    if (t < 256) {
        const int j = t & 15, k = t >> 4;
        float s[4] = {0.f, 0.f, 0.f, 0.f};
        #pragma unroll
        for (int m = 0; m < DIM; ++m) {
            const float rr = Ulds[(m * DIM + j) * 2 + 0] * Ulds[(m * DIM + k) * 2 + 0]
                           + Ulds[(m * DIM + j) * 2 + 1] * Ulds[(m * DIM + k) * 2 + 1];
            #pragma unroll
            for (int q = 0; q < 4; ++q)
                s[q] += ((m >> (3 - q)) & 1) ? -rr : rr;
        }
        #pragma unroll
        for (int q = 0; q < 4; ++q) ReMs[(k * DIM + j) * 4 + q] = s[q];
    }
    __syncthreads();

    if (t < 324) {
        const int q = t & 3;
        const int r = t >> 2;                 // 0..80
        int e[4];
        e[3] = r % 3; e[2] = (r / 3) % 3; e[1] = (r / 9) % 3; e[0] = r / 27;
        float sum = 0.f;
        #pragma unroll
        for (int o = 0; o < 16; ++o) {
            int j = 0, k = 0; float wgt = 1.f;
            #pragma unroll
            for (int i = 0; i < 4; ++i) {
                const int oi = (o >> i) & 1;
                int bj, bk; float wi;
                if (e[i] == 0)      { bj = oi; bk = oi;     wi = 0.5f; }
                else if (e[i] == 1) { bj = oi; bk = oi;     wi = oi ? -0.5f : 0.5f; }
                else                { bj = oi; bk = oi ^ 1; wi = 0.5f; }
                j |= bj << (3 - i); k |= bk << (3 - i); wgt *= wi;
            }
            sum += wgt * ReMs[(k * DIM + j) * 4 + q];
        }
        Cg[r * 4 + q] = sum;
    }
}

// ---------------------------------------------------------------------------
// Main kernel, round 12. r8/r9 algebra: q ~= 7us + 0.21us * (table loads per
// element) -> the residual IS per-instruction VMEM issue cost of uniform
// loads. Fix: read the table through a CONSTANT address-space (AS4) pointer.
// Uniform address + AS4 -> backend emits s_load_dwordx4 (merged to x16 by
// SILoadStoreOptimizer) into SGPRs on the SCALAR pipe; v_fma folds the
// single SGPR operand. No inline asm (r11's hand-allocated tuples crashed).
// a,b loops unroll 1 -> one 36-dword block live (36 SGPR, no spill).
// ELEM=2 hedge: if scalarization fails this degrades to ~r9-class VMEM code.
// POD ext_vector f4v everywhere (HIP float4 has ctors -> AS-mismatch).
// ---------------------------------------------------------------------------
__global__ __launch_bounds__(TPB) void qsim(const f4v* __restrict__ x,
                                            const float* __restrict__ Cg,
                                            f4v* __restrict__ out, int T) {
    const int tid = blockIdx.x * TPB + threadIdx.x;
    if (tid >= T) return;

    const f4v xa = x[tid];
    const f4v xb = x[tid + T];
    const float ca0 = hcos(xa.x), sa0 = hsin(xa.x);
    const float ca1 = hcos(xa.y), sa1 = hsin(xa.y);
    const float ca2 = hcos(xa.z), sa2 = hsin(xa.z);
    const float ca3 = hcos(xa.w), sa3 = hsin(xa.w);
    const float cb0 = hcos(xb.x), sb0 = hsin(xb.x);
    const float cb1 = hcos(xb.y), sb1 = hsin(xb.y);
    const float cb2 = hcos(xb.z), sb2 = hsin(xb.z);
    const float cb3 = hcos(xb.w), sb3 = hsin(xb.w);

    // basis products over qubits 2,3: m=1..8 (m=0 is the constant-1 term)
    const float A1 = ca3, A2 = sa3, A3 = ca2, A4 = ca2 * ca3;
    const float A5 = ca2 * sa3, A6 = sa2, A7 = sa2 * ca3, A8 = sa2 * sa3;
    const float B1 = cb3, B2 = sb3, B3 = cb2, B4 = cb2 * cb3;
    const float B5 = cb2 * sb3, B6 = sb2, B7 = sb2 * cb3, B8 = sb2 * sb3;

    f4v accA = {0.f, 0.f, 0.f, 0.f};
    f4v accB = {0.f, 0.f, 0.f, 0.f};

    // Constant-address-space view of the table -> scalar (s_load) path.
    const __attribute__((address_space(4))) f4v* Ck =
        (const __attribute__((address_space(4))) f4v*)Cg;

    #pragma unroll 1
    for (int a = 0; a < 3; ++a) {
        const float waA = (a == 0) ? 1.f : ((a == 1) ? ca0 : sa0);
        const float waB = (a == 0) ? 1.f : ((a == 1) ? cb0 : sb0);
        #pragma unroll 1
        for (int b = 0; b < 3; ++b) {
            const float wabA = waA * ((b == 0) ? 1.f : ((b == 1) ? ca1 : sa1));
            const float wabB = waB * ((b == 0) ? 1.f : ((b == 1) ? cb1 : sb1));

            f4v L[9];
            #pragma unroll
            for (int m = 0; m < 9; ++m) L[m] = Ck[(a * 3 + b) * 9 + m];

            f4v TA = L[0];
            TA = vfma(L[1], A1, TA); TA = vfma(L[2], A2, TA);
            TA = vfma(L[3], A3, TA); TA = vfma(L[4], A4, TA);
            TA = vfma(L[5], A5, TA); TA = vfma(L[6], A6, TA);
            TA = vfma(L[7], A7, TA); TA = vfma(L[8], A8, TA);
            accA = vfma(TA, wabA, accA);

            f4v TB = L[0];
            TB = vfma(L[1], B1, TB); TB = vfma(L[2], B2, TB);
            TB = vfma(L[3], B3, TB); TB = vfma(L[4], B4, TB);
            TB = vfma(L[5], B5, TB); TB = vfma(L[6], B6, TB);
            TB = vfma(L[7], B7, TB); TB = vfma(L[8], B8, TB);
            accB = vfma(TB, wabB, accB);
        }
    }

    out[tid] = accA;
    out[tid + T] = accB;
}

extern "C" void kernel_launch(void* const* d_in, const int* in_sizes, int n_in,
                              void* d_out, int out_size, void* d_ws, size_t ws_size,
                              hipStream_t stream) {
    const float* x = (const float*)d_in[0];   // (B, 4) f32
    const float* w = (const float*)d_in[1];   // (6, 4, 3) f32
    float* Cg = (float*)d_ws;                 // 81 * float4 = 1296 B
    const int B = in_sizes[0] / NQ;           // 1048576
    const int T = B / 2;                      // ELEM=2

    build_all<<<1, 384, 0, stream>>>(w, Cg);
    qsim<<<(T + TPB - 1) / TPB, TPB, 0, stream>>>((const f4v*)x, Cg,
                                                  (f4v*)d_out, T);
}